// Round 1
// baseline (307.198 us; speedup 1.0000x reference)
//
#include <hip/hip_runtime.h>

#define D_IN 32768
#define D_OUT 128
#define NB 4096
#define NKC 8
#define KC (D_IN / NKC)   // 4096
#define BM 128
#define BK 64

typedef short short8 __attribute__((ext_vector_type(8)));
typedef __bf16 bf16x8 __attribute__((ext_vector_type(8)));
typedef float f32x4 __attribute__((ext_vector_type(4)));

__device__ __forceinline__ unsigned short f2bf(float f) {
  unsigned int u = __builtin_bit_cast(unsigned int, f);
  u += 0x7fffu + ((u >> 16) & 1u);
  return (unsigned short)(u >> 16);
}

// swizzled element offset within a [rows][64] bf16 LDS tile (16B-slot XOR)
__device__ __forceinline__ int swz(int r, int c) {
  return r * BK + (c ^ ((r & 7) << 3));
}

// ---------------------------------------------------------------------------
// prep: mean_pre/var_pre -> bf16 combined weights [256][32768]; KL reduction
// ---------------------------------------------------------------------------
__global__ void prep_kernel(const float* __restrict__ mu, const float* __restrict__ sg,
                            const float* __restrict__ sp, const float* __restrict__ pg,
                            unsigned short* __restrict__ wcomb, float* __restrict__ kl_acc) {
  const int NV = D_OUT * D_IN / 4;  // float4 groups
  float kl = 0.f;
  for (int i = blockIdx.x * blockDim.x + threadIdx.x; i < NV; i += gridDim.x * blockDim.x) {
    const int e = i * 4;
    const int r = e >> 15;           // row in [0,128)
    const int c = e & (D_IN - 1);
    const float4 m4 = *(const float4*)(mu + e);
    const float4 s4 = *(const float4*)(sg + e);
    const float4 p4 = *(const float4*)(sp + e);
    const float4 g4 = *(const float4*)(pg + e);
    const float mv[4] = {m4.x, m4.y, m4.z, m4.w};
    const float sv[4] = {s4.x, s4.y, s4.z, s4.w};
    const float pv4[4] = {p4.x, p4.y, p4.z, p4.w};
    const float gv[4] = {g4.x, g4.y, g4.z, g4.w};
    ushort4 mo, vo;
    unsigned short* mop = (unsigned short*)&mo;
    unsigned short* vop = (unsigned short*)&vo;
#pragma unroll
    for (int j = 0; j < 4; ++j) {
      const float m_ = mv[j];
      const float s_ = fmaxf(sv[j], 1e-12f);              // relu + clamp(min=eps)
      const float p_ = fminf(fmaxf(pv4[j], 1e-6f), 1.f - 1e-6f);
      const float pvar = gv[j] * gv[j];
      const float mean = p_ * m_;
      const float var = p_ * s_ * s_ + p_ * (1.f - p_) * m_ * m_;
      mop[j] = f2bf(mean);
      vop[j] = f2bf(var);
      const float rr = (s_ * s_) / pvar;                  // sig^2 / prior_var
      kl += -0.5f * p_ * (1.f + logf(rr) - (m_ * m_) / pvar - rr);
      kl += (1.f - p_) * logf((1.f - p_) / 0.9f) + p_ * logf(p_ / 0.1f);
    }
    *(ushort4*)(wcomb + (size_t)r * D_IN + c) = mo;                  // mean rows 0..127
    *(ushort4*)(wcomb + (size_t)(D_OUT + r) * D_IN + c) = vo;        // var rows 128..255
  }
  // block reduction of kl
#pragma unroll
  for (int off = 32; off > 0; off >>= 1) kl += __shfl_down(kl, off);
  __shared__ float red[4];
  const int lane = threadIdx.x & 63;
  const int wid = threadIdx.x >> 6;
  if (lane == 0) red[wid] = kl;
  __syncthreads();
  if (threadIdx.x == 0) atomicAdd(kl_acc, red[0] + red[1] + red[2] + red[3]);
}

// ---------------------------------------------------------------------------
// GEMM: per block 128 rows x 256 cols (mean|var) x 4096 K-chunk, bf16 MFMA
// ---------------------------------------------------------------------------
__global__ __launch_bounds__(512, 1) void gemm_kernel(const float* __restrict__ x,
                                                      const unsigned short* __restrict__ wcomb,
                                                      float* __restrict__ partial) {
  __shared__ unsigned short xab[2 * BM * BK];    // [0..8191]=bf16(x), [8192..]=bf16(x^2)
  __shared__ unsigned short wl[2 * D_OUT * BK];  // 256 weight rows

  const int bid = blockIdx.x;
  const int kc = bid & (NKC - 1);   // K-chunk == XCD (round-robin) -> weight chunk L2-resident
  const int mb = bid >> 3;
  const int m0 = mb * BM;
  const size_t k0 = (size_t)kc * KC;

  const int t = threadIdx.x;
  const int lane = t & 63;
  const int wid = t >> 6;
  const int wm = wid >> 2;          // 0..1: M half (64 rows)
  const int wn = wid & 3;           // 0..3: N quarter of 256 (0,1=mean; 2,3=var)

  const int xrow = t >> 4;          // 0..31
  const int xc4 = (t & 15) << 2;    // 0..60
  const int wrow = t >> 3;          // 0..63
  const int wc8 = (t & 7) << 3;     // 0..56

  const float* xg = x + (size_t)m0 * D_IN + k0;
  const unsigned short* wg = wcomb + k0;

  float4 xr[4];
  uint4 wr[4];

  f32x4 acc[4][4];
#pragma unroll
  for (int i = 0; i < 4; ++i)
#pragma unroll
    for (int j = 0; j < 4; ++j) acc[i][j] = (f32x4){0.f, 0.f, 0.f, 0.f};

  // prologue loads for ks=0
#pragma unroll
  for (int p = 0; p < 4; ++p)
    xr[p] = *(const float4*)(xg + (size_t)(xrow + p * 32) * D_IN + xc4);
#pragma unroll
  for (int p = 0; p < 4; ++p)
    wr[p] = *(const uint4*)(wg + (size_t)(wrow + p * 64) * D_IN + wc8);

  const unsigned short* asrc = xab + ((wn >= 2) ? (BM * BK) : 0);
  const int a0 = wm * 64;
  const int b0 = wn * 64;
  const int l15 = lane & 15;
  const int lk = (lane >> 4) << 3;

  for (int ks = 0; ks < KC; ks += BK) {
    // write staged regs -> LDS (convert x -> bf16, x^2 -> bf16)
#pragma unroll
    for (int p = 0; p < 4; ++p) {
      const int r = xrow + p * 32;
      const float4 v = xr[p];
      const float vv[4] = {v.x, v.y, v.z, v.w};
      ushort4 a, s;
      unsigned short* ap = (unsigned short*)&a;
      unsigned short* spp = (unsigned short*)&s;
#pragma unroll
      for (int j = 0; j < 4; ++j) {
        ap[j] = f2bf(vv[j]);
        spp[j] = f2bf(vv[j] * vv[j]);
      }
      const int idx = swz(r, xc4);
      *(ushort4*)(xab + idx) = a;
      *(ushort4*)(xab + BM * BK + idx) = s;
    }
#pragma unroll
    for (int p = 0; p < 4; ++p) {
      const int r = wrow + p * 64;
      *(uint4*)(wl + swz(r, wc8)) = wr[p];
    }
    __syncthreads();

    // prefetch next tile into registers (overlaps with MFMA below)
    if (ks + BK < KC) {
#pragma unroll
      for (int p = 0; p < 4; ++p)
        xr[p] = *(const float4*)(xg + (size_t)(xrow + p * 32) * D_IN + (ks + BK) + xc4);
#pragma unroll
      for (int p = 0; p < 4; ++p)
        wr[p] = *(const uint4*)(wg + (size_t)(wrow + p * 64) * D_IN + (ks + BK) + wc8);
    }

    bf16x8 af[4][2], bfr[4][2];
#pragma unroll
    for (int mi = 0; mi < 4; ++mi)
#pragma unroll
      for (int kk = 0; kk < 2; ++kk)
        af[mi][kk] = *(const bf16x8*)(asrc + swz(a0 + mi * 16 + l15, kk * 32 + lk));
#pragma unroll
    for (int ni = 0; ni < 4; ++ni)
#pragma unroll
      for (int kk = 0; kk < 2; ++kk)
        bfr[ni][kk] = *(const bf16x8*)(wl + swz(b0 + ni * 16 + l15, kk * 32 + lk));

#pragma unroll
    for (int mi = 0; mi < 4; ++mi)
#pragma unroll
      for (int ni = 0; ni < 4; ++ni)
#pragma unroll
        for (int kk = 0; kk < 2; ++kk)
          acc[mi][ni] = __builtin_amdgcn_mfma_f32_16x16x32_bf16(af[mi][kk], bfr[ni][kk],
                                                                acc[mi][ni], 0, 0, 0);
    __syncthreads();
  }

  // epilogue: write partial [kc][4096][256]
  float* pp = partial + (size_t)kc * ((size_t)NB * 2 * D_OUT);
  const int crow = (lane >> 4) << 2;
  const int ccol = lane & 15;
#pragma unroll
  for (int mi = 0; mi < 4; ++mi) {
    const int grow = m0 + wm * 64 + mi * 16 + crow;
#pragma unroll
    for (int ni = 0; ni < 4; ++ni) {
      const int gcol = wn * 64 + ni * 16 + ccol;
      const f32x4 a = acc[mi][ni];
#pragma unroll
      for (int j = 0; j < 4; ++j)
        pp[(size_t)(grow + j) * (2 * D_OUT) + gcol] = a[j];
    }
  }
}

// ---------------------------------------------------------------------------
// reduce: sum K-chunk partials, out = m +/- eps*sqrt(v), append kl
// ---------------------------------------------------------------------------
__global__ void reduce_kernel(const float* __restrict__ partial,
                              const float* __restrict__ eps,
                              const float* __restrict__ kl_acc,
                              float* __restrict__ out) {
  const int tid = blockIdx.x * blockDim.x + threadIdx.x;
  if (tid == 0) out[2 * NB * D_OUT] = kl_acc[0] * (1.0f / 4096.0f);
  if (tid >= NB * D_OUT / 4) return;
  const int b = tid >> 5;
  const int j = (tid & 31) << 2;
  float m[4] = {0.f, 0.f, 0.f, 0.f}, v[4] = {0.f, 0.f, 0.f, 0.f};
#pragma unroll
  for (int q = 0; q < NKC; ++q) {
    const float* p = partial + ((size_t)q * NB + b) * (2 * D_OUT);
    const float4 mm = *(const float4*)(p + j);
    const float4 vv = *(const float4*)(p + D_OUT + j);
    m[0] += mm.x; m[1] += mm.y; m[2] += mm.z; m[3] += mm.w;
    v[0] += vv.x; v[1] += vv.y; v[2] += vv.z; v[3] += vv.w;
  }
  const float4 e4 = *(const float4*)(eps + (size_t)b * D_OUT + j);
  const float ev[4] = {e4.x, e4.y, e4.z, e4.w};
  float4 o0, o1;
  float* o0p = (float*)&o0;
  float* o1p = (float*)&o1;
#pragma unroll
  for (int jj = 0; jj < 4; ++jj) {
    const float s = ev[jj] * sqrtf(fmaxf(v[jj], 0.f));
    o0p[jj] = m[jj] + s;
    o1p[jj] = m[jj] - s;
  }
  *(float4*)(out + (size_t)b * D_OUT + j) = o0;
  *(float4*)(out + (size_t)NB * D_OUT + (size_t)b * D_OUT + j) = o1;
}

extern "C" void kernel_launch(void* const* d_in, const int* in_sizes, int n_in,
                              void* d_out, int out_size, void* d_ws, size_t ws_size,
                              hipStream_t stream) {
  const float* x   = (const float*)d_in[0];
  const float* mu  = (const float*)d_in[1];
  const float* sg  = (const float*)d_in[2];
  const float* sp  = (const float*)d_in[3];
  const float* pg  = (const float*)d_in[4];
  const float* eps = (const float*)d_in[5];
  float* out = (float*)d_out;

  // ws layout: [0,16MiB) bf16 weights [256][32768]; [16MiB,48MiB) partials
  // [8][4096][256] f32; [48MiB] kl accumulator
  unsigned short* wcomb = (unsigned short*)d_ws;
  float* partial = (float*)((char*)d_ws + (size_t)16 * 1024 * 1024);
  float* kl_acc = (float*)((char*)d_ws + (size_t)48 * 1024 * 1024);

  hipMemsetAsync(kl_acc, 0, sizeof(float), stream);
  prep_kernel<<<2048, 256, 0, stream>>>(mu, sg, sp, pg, wcomb, kl_acc);
  gemm_kernel<<<(NB / BM) * NKC, 512, 0, stream>>>(x, wcomb, partial);
  reduce_kernel<<<(NB * D_OUT / 4) / 256, 256, 0, stream>>>(partial, eps, kl_acc, out);
}

// Round 2
// 129.062 us; speedup vs baseline: 2.3802x; 2.3802x over previous
//
#include <hip/hip_runtime.h>

#define D_IN 32768
#define D_OUT 128
#define NB 4096
#define NKC 8
#define KC (D_IN / NKC)     // 4096
#define BM 128
#define BK 64
#define NSTEP (KC / BK)     // 64

typedef __bf16 bf16x8 __attribute__((ext_vector_type(8)));
typedef __bf16 bf16x4 __attribute__((ext_vector_type(4)));
typedef float f32x4 __attribute__((ext_vector_type(4)));

// swizzled element offset within a [rows][64] bf16 tile (16B-slot XOR)
__device__ __forceinline__ int swz(int r, int c) {
  return r * BK + (c ^ ((r & 7) << 3));
}

// ---------------------------------------------------------------------------
// prep: mean_pre/var_pre -> bf16 combined weights [256][32768]; KL reduction
// ---------------------------------------------------------------------------
__global__ void prep_kernel(const float* __restrict__ mu, const float* __restrict__ sg,
                            const float* __restrict__ sp, const float* __restrict__ pg,
                            __bf16* __restrict__ wcomb, float* __restrict__ kl_acc) {
  const int NV = D_OUT * D_IN / 4;  // float4 groups
  float kl = 0.f;
  for (int i = blockIdx.x * blockDim.x + threadIdx.x; i < NV; i += gridDim.x * blockDim.x) {
    const int e = i * 4;
    const int r = e >> 15;           // row in [0,128)
    const int c = e & (D_IN - 1);
    const float4 m4 = *(const float4*)(mu + e);
    const float4 s4 = *(const float4*)(sg + e);
    const float4 p4 = *(const float4*)(sp + e);
    const float4 g4 = *(const float4*)(pg + e);
    const float mv[4] = {m4.x, m4.y, m4.z, m4.w};
    const float sv[4] = {s4.x, s4.y, s4.z, s4.w};
    const float pv4[4] = {p4.x, p4.y, p4.z, p4.w};
    const float gv[4] = {g4.x, g4.y, g4.z, g4.w};
    bf16x4 mo, vo;
#pragma unroll
    for (int j = 0; j < 4; ++j) {
      const float m_ = mv[j];
      const float s_ = fmaxf(sv[j], 1e-12f);              // relu + clamp(min=eps)
      const float p_ = fminf(fmaxf(pv4[j], 1e-6f), 1.f - 1e-6f);
      const float pvar = gv[j] * gv[j];
      const float mean = p_ * m_;
      const float var = p_ * s_ * s_ + p_ * (1.f - p_) * m_ * m_;
      mo[j] = (__bf16)mean;
      vo[j] = (__bf16)var;
      const float rr = (s_ * s_) / pvar;                  // sig^2 / prior_var
      kl += -0.5f * p_ * (1.f + __logf(rr) - (m_ * m_) / pvar - rr);
      kl += (1.f - p_) * __logf((1.f - p_) * (1.f / 0.9f)) + p_ * __logf(p_ * 10.f);
    }
    *(bf16x4*)(wcomb + (size_t)r * D_IN + c) = mo;                 // mean rows 0..127
    *(bf16x4*)(wcomb + (size_t)(D_OUT + r) * D_IN + c) = vo;       // var rows 128..255
  }
  // block reduction of kl
#pragma unroll
  for (int off = 32; off > 0; off >>= 1) kl += __shfl_down(kl, off);
  __shared__ float red[4];
  const int lane = threadIdx.x & 63;
  const int wid = threadIdx.x >> 6;
  if (lane == 0) red[wid] = kl;
  __syncthreads();
  if (threadIdx.x == 0) atomicAdd(kl_acc, red[0] + red[1] + red[2] + red[3]);
}

// ---------------------------------------------------------------------------
// GEMM: block = 128 rows x 256 cols (mean|var) x 4096 K-chunk.
// 16 waves (1024 thr), wave tile 32x64. Double-buffered LDS (128 KiB),
// ONE raw s_barrier per K-step, no vmcnt drain in loop (prefetch regs stay
// in flight across the barrier; compiler inserts precise vmcnt on use).
// ---------------------------------------------------------------------------
__global__ __launch_bounds__(1024, 4) void gemm_kernel(const float* __restrict__ x,
                                                       const __bf16* __restrict__ wcomb,
                                                       float* __restrict__ partial) {
  // per buffer (32768 bf16 = 64 KiB): [0,8192)=bf16(x) [128][64],
  // [8192,16384)=bf16(x^2) [128][64], [16384,32768)=w [256][64]
  __shared__ __bf16 lds[2][32768];

  const int bid = blockIdx.x;
  const int kc = bid & (NKC - 1);   // K-chunk == XCD (round-robin): w chunk L2-resident
  const int mb = bid >> 3;
  const int m0 = mb * BM;
  const size_t k0 = (size_t)kc * KC;

  const int t = threadIdx.x;
  const int lane = t & 63;
  const int wid = t >> 6;           // 0..15
  const int wm = wid >> 2;          // 0..3: 32-row strip
  const int wn = wid & 3;           // 0..3: 64-col strip (0,1=mean; 2,3=var)

  // staging indices
  const int xrow = t >> 3;          // 0..127
  const int xc = (t & 7) << 3;      // 0..56, 8 floats per thread
  const int wrow = t >> 2;          // 0..255
  const int wc = (t & 3) << 4;      // 0..48, 16 bf16 per thread

  const float* xg = x + (size_t)xrow * D_IN + k0 + xc;
  const __bf16* wg = wcomb + (size_t)wrow * D_IN + k0 + wc;

  const int xoff = swz(xrow, xc);                 // within XA region
  const int woff0 = 16384 + swz(wrow, wc);
  const int woff1 = 16384 + swz(wrow, wc + 8);

  f32x4 acc[2][4];
#pragma unroll
  for (int i = 0; i < 2; ++i)
#pragma unroll
    for (int j = 0; j < 4; ++j) acc[i][j] = (f32x4){0.f, 0.f, 0.f, 0.f};

  const int l15 = lane & 15;
  const int lk = (lane >> 4) << 3;
  const int abase = (wn >= 2) ? 8192 : 0;         // mean waves: bf16(x); var: bf16(x^2)
  const int ar0 = wm * 32 + l15;
  const int br0 = wn * 64 + l15;

  // prologue: issue loads for step 0
  float4 xr0 = *(const float4*)(xg);
  float4 xr1 = *(const float4*)(xg + 4);
  uint4 wr0 = *(const uint4*)(wg);
  uint4 wr1 = *(const uint4*)(wg + 8);

  for (int i = 0; i < NSTEP; ++i) {
    __bf16* buf = lds[i & 1];

    // stage regs -> LDS (waits vmcnt for xr/wr automatically)
    {
      const float vv[8] = {xr0.x, xr0.y, xr0.z, xr0.w, xr1.x, xr1.y, xr1.z, xr1.w};
      bf16x8 a, s;
#pragma unroll
      for (int j = 0; j < 8; ++j) {
        const float f = vv[j];
        a[j] = (__bf16)f;
        s[j] = (__bf16)(f * f);
      }
      *(bf16x8*)(buf + xoff) = a;
      *(bf16x8*)(buf + 8192 + xoff) = s;
      *(uint4*)(buf + woff0) = wr0;
      *(uint4*)(buf + woff1) = wr1;
    }

    // issue next-step loads; they stay in flight across the barrier
    if (i + 1 < NSTEP) {
      const int kn = (i + 1) * BK;
      xr0 = *(const float4*)(xg + kn);
      xr1 = *(const float4*)(xg + kn + 4);
      wr0 = *(const uint4*)(wg + kn);
      wr1 = *(const uint4*)(wg + kn + 8);
    }

    asm volatile("s_waitcnt lgkmcnt(0)" ::: "memory");  // ds_writes visible
    __builtin_amdgcn_s_barrier();                       // raw: does NOT drain vmcnt

    // fragments + MFMA from buf
#pragma unroll
    for (int kk = 0; kk < 2; ++kk) {
      const int col = kk * 32 + lk;
      bf16x8 af[2], bfv[4];
#pragma unroll
      for (int mi = 0; mi < 2; ++mi)
        af[mi] = *(const bf16x8*)(buf + abase + swz(ar0 + mi * 16, col));
#pragma unroll
      for (int ni = 0; ni < 4; ++ni)
        bfv[ni] = *(const bf16x8*)(buf + 16384 + swz(br0 + ni * 16, col));
#pragma unroll
      for (int mi = 0; mi < 2; ++mi)
#pragma unroll
        for (int ni = 0; ni < 4; ++ni)
          acc[mi][ni] = __builtin_amdgcn_mfma_f32_16x16x32_bf16(af[mi], bfv[ni],
                                                                acc[mi][ni], 0, 0, 0);
    }
    // no trailing barrier: next step writes the OTHER buffer; reuse of this
    // buffer (step i+2) is fenced by step i+1's lgkmcnt(0)+barrier.
  }

  // epilogue: write partial [kc][4096][256]
  float* pp = partial + (size_t)kc * ((size_t)NB * 2 * D_OUT);
  const int crow = (lane >> 4) << 2;
  const int ccol = lane & 15;
#pragma unroll
  for (int mi = 0; mi < 2; ++mi) {
    const int grow = m0 + wm * 32 + mi * 16 + crow;
#pragma unroll
    for (int ni = 0; ni < 4; ++ni) {
      const int gcol = wn * 64 + ni * 16 + ccol;
      const f32x4 a = acc[mi][ni];
#pragma unroll
      for (int j = 0; j < 4; ++j)
        pp[(size_t)(grow + j) * (2 * D_OUT) + gcol] = a[j];
    }
  }
}

// ---------------------------------------------------------------------------
// reduce: sum K-chunk partials, out = m +/- eps*sqrt(v), append kl
// ---------------------------------------------------------------------------
__global__ void reduce_kernel(const float* __restrict__ partial,
                              const float* __restrict__ eps,
                              const float* __restrict__ kl_acc,
                              float* __restrict__ out) {
  const int tid = blockIdx.x * blockDim.x + threadIdx.x;
  if (tid == 0) out[2 * NB * D_OUT] = kl_acc[0] * (1.0f / 4096.0f);
  if (tid >= NB * D_OUT / 4) return;
  const int b = tid >> 5;
  const int j = (tid & 31) << 2;
  float m[4] = {0.f, 0.f, 0.f, 0.f}, v[4] = {0.f, 0.f, 0.f, 0.f};
#pragma unroll
  for (int q = 0; q < NKC; ++q) {
    const float* p = partial + ((size_t)q * NB + b) * (2 * D_OUT);
    const float4 mm = *(const float4*)(p + j);
    const float4 vv = *(const float4*)(p + D_OUT + j);
    m[0] += mm.x; m[1] += mm.y; m[2] += mm.z; m[3] += mm.w;
    v[0] += vv.x; v[1] += vv.y; v[2] += vv.z; v[3] += vv.w;
  }
  const float4 e4 = *(const float4*)(eps + (size_t)b * D_OUT + j);
  const float ev[4] = {e4.x, e4.y, e4.z, e4.w};
  float4 o0, o1;
  float* o0p = (float*)&o0;
  float* o1p = (float*)&o1;
#pragma unroll
  for (int jj = 0; jj < 4; ++jj) {
    const float s = ev[jj] * sqrtf(fmaxf(v[jj], 0.f));
    o0p[jj] = m[jj] + s;
    o1p[jj] = m[jj] - s;
  }
  *(float4*)(out + (size_t)b * D_OUT + j) = o0;
  *(float4*)(out + (size_t)NB * D_OUT + (size_t)b * D_OUT + j) = o1;
}

extern "C" void kernel_launch(void* const* d_in, const int* in_sizes, int n_in,
                              void* d_out, int out_size, void* d_ws, size_t ws_size,
                              hipStream_t stream) {
  const float* x   = (const float*)d_in[0];
  const float* mu  = (const float*)d_in[1];
  const float* sg  = (const float*)d_in[2];
  const float* sp  = (const float*)d_in[3];
  const float* pg  = (const float*)d_in[4];
  const float* eps = (const float*)d_in[5];
  float* out = (float*)d_out;

  // ws layout: [0,16MiB) bf16 weights [256][32768]; [16MiB,48MiB) partials
  // [8][4096][256] f32; [48MiB] kl accumulator
  __bf16* wcomb = (__bf16*)d_ws;
  float* partial = (float*)((char*)d_ws + (size_t)16 * 1024 * 1024);
  float* kl_acc = (float*)((char*)d_ws + (size_t)48 * 1024 * 1024);

  hipMemsetAsync(kl_acc, 0, sizeof(float), stream);
  prep_kernel<<<2048, 256, 0, stream>>>(mu, sg, sp, pg, wcomb, kl_acc);
  gemm_kernel<<<(NB / BM) * NKC, 1024, 0, stream>>>(x, wcomb, partial);
  reduce_kernel<<<(NB * D_OUT / 4) / 256, 256, 0, stream>>>(partial, eps, kl_acc, out);
}

// Round 3
// 104.312 us; speedup vs baseline: 2.9450x; 1.2373x over previous
//
#include <hip/hip_runtime.h>

#define D_IN 32768
#define D_OUT 128
#define NB 4096
#define NKC 8
#define KC (D_IN / NKC)     // 4096
#define BM 128
#define BK 64
#define NSTEP (KC / BK)     // 64
#define PREP_BLOCKS 2048

typedef __bf16 bf16x8 __attribute__((ext_vector_type(8)));
typedef __bf16 bf16x4 __attribute__((ext_vector_type(4)));
typedef float f32x4 __attribute__((ext_vector_type(4)));
typedef _Float16 half4 __attribute__((ext_vector_type(4)));

// swizzled element offset within a [rows][64] bf16 tile (16B-slot XOR)
__device__ __forceinline__ int swz(int r, int c) {
  return r * BK + (c ^ ((r & 7) << 3));
}

// ---------------------------------------------------------------------------
// prep: mean_pre/var_pre -> bf16 combined weights [256][32768]; KL partials
// ---------------------------------------------------------------------------
__global__ void prep_kernel(const float* __restrict__ mu, const float* __restrict__ sg,
                            const float* __restrict__ sp, const float* __restrict__ pg,
                            __bf16* __restrict__ wcomb, float* __restrict__ kl_part) {
  const int NV = D_OUT * D_IN / 4;  // float4 groups
  float kl = 0.f;
  for (int i = blockIdx.x * blockDim.x + threadIdx.x; i < NV; i += gridDim.x * blockDim.x) {
    const int e = i * 4;
    const int r = e >> 15;           // row in [0,128)
    const int c = e & (D_IN - 1);
    const float4 m4 = *(const float4*)(mu + e);
    const float4 s4 = *(const float4*)(sg + e);
    const float4 p4 = *(const float4*)(sp + e);
    const float4 g4 = *(const float4*)(pg + e);
    const float mv[4] = {m4.x, m4.y, m4.z, m4.w};
    const float sv[4] = {s4.x, s4.y, s4.z, s4.w};
    const float pv4[4] = {p4.x, p4.y, p4.z, p4.w};
    const float gv[4] = {g4.x, g4.y, g4.z, g4.w};
    bf16x4 mo, vo;
#pragma unroll
    for (int j = 0; j < 4; ++j) {
      const float m_ = mv[j];
      const float s_ = fmaxf(sv[j], 1e-12f);              // relu + clamp(min=eps)
      const float p_ = fminf(fmaxf(pv4[j], 1e-6f), 1.f - 1e-6f);
      const float pvar = gv[j] * gv[j];
      const float mean = p_ * m_;
      const float var = p_ * s_ * s_ + p_ * (1.f - p_) * m_ * m_;
      mo[j] = (__bf16)mean;
      vo[j] = (__bf16)var;
      const float rr = (s_ * s_) / pvar;                  // sig^2 / prior_var
      kl += -0.5f * p_ * (1.f + __logf(rr) - (m_ * m_) / pvar - rr);
      kl += (1.f - p_) * __logf((1.f - p_) * (1.f / 0.9f)) + p_ * __logf(p_ * 10.f);
    }
    *(bf16x4*)(wcomb + (size_t)r * D_IN + c) = mo;                 // mean rows 0..127
    *(bf16x4*)(wcomb + (size_t)(D_OUT + r) * D_IN + c) = vo;       // var rows 128..255
  }
  // block reduction of kl -> per-block partial (deterministic, no atomics)
#pragma unroll
  for (int off = 32; off > 0; off >>= 1) kl += __shfl_down(kl, off);
  __shared__ float red[4];
  const int lane = threadIdx.x & 63;
  const int wid = threadIdx.x >> 6;
  if (lane == 0) red[wid] = kl;
  __syncthreads();
  if (threadIdx.x == 0) kl_part[blockIdx.x] = red[0] + red[1] + red[2] + red[3];
}

// ---------------------------------------------------------------------------
// GEMM: block = 128 rows x 256 cols (mean|var) x 4096 K-chunk.
// 16 waves (1024 thr), wave tile 32x64. Double-buffered LDS (128 KiB),
// ONE raw s_barrier per K-step, no vmcnt drain in loop. Partials in f16.
// ---------------------------------------------------------------------------
__global__ __launch_bounds__(1024, 4) void gemm_kernel(const float* __restrict__ x,
                                                       const __bf16* __restrict__ wcomb,
                                                       _Float16* __restrict__ partial) {
  // per buffer (32768 bf16 = 64 KiB): [0,8192)=bf16(x) [128][64],
  // [8192,16384)=bf16(x^2) [128][64], [16384,32768)=w [256][64]
  __shared__ __bf16 lds[2][32768];

  const int bid = blockIdx.x;
  const int kc = bid & (NKC - 1);   // K-chunk == XCD (round-robin): w chunk L2-resident
  const int mb = bid >> 3;
  const int m0 = mb * BM;
  const size_t k0 = (size_t)kc * KC;

  const int t = threadIdx.x;
  const int lane = t & 63;
  const int wid = t >> 6;           // 0..15
  const int wm = wid >> 2;          // 0..3: 32-row strip
  const int wn = wid & 3;           // 0..3: 64-col strip (0,1=mean; 2,3=var)

  // staging indices
  const int xrow = t >> 3;          // 0..127
  const int xc = (t & 7) << 3;      // 0..56, 8 floats per thread
  const int wrow = t >> 2;          // 0..255
  const int wc = (t & 3) << 4;      // 0..48, 16 bf16 per thread

  const float* xg = x + (size_t)xrow * D_IN + k0 + xc;
  const __bf16* wg = wcomb + (size_t)wrow * D_IN + k0 + wc;

  const int xoff = swz(xrow, xc);                 // within XA region
  const int woff0 = 16384 + swz(wrow, wc);
  const int woff1 = 16384 + swz(wrow, wc + 8);

  f32x4 acc[2][4];
#pragma unroll
  for (int i = 0; i < 2; ++i)
#pragma unroll
    for (int j = 0; j < 4; ++j) acc[i][j] = (f32x4){0.f, 0.f, 0.f, 0.f};

  const int l15 = lane & 15;
  const int lk = (lane >> 4) << 3;
  const int abase = (wn >= 2) ? 8192 : 0;         // mean waves: bf16(x); var: bf16(x^2)
  const int ar0 = wm * 32 + l15;
  const int br0 = wn * 64 + l15;

  // prologue: issue loads for step 0
  float4 xr0 = *(const float4*)(xg);
  float4 xr1 = *(const float4*)(xg + 4);
  uint4 wr0 = *(const uint4*)(wg);
  uint4 wr1 = *(const uint4*)(wg + 8);

  for (int i = 0; i < NSTEP; ++i) {
    __bf16* buf = lds[i & 1];

    // stage regs -> LDS (waits vmcnt for xr/wr automatically)
    {
      const float vv[8] = {xr0.x, xr0.y, xr0.z, xr0.w, xr1.x, xr1.y, xr1.z, xr1.w};
      bf16x8 a, s;
#pragma unroll
      for (int j = 0; j < 8; ++j) {
        const float f = vv[j];
        a[j] = (__bf16)f;
        s[j] = (__bf16)(f * f);
      }
      *(bf16x8*)(buf + xoff) = a;
      *(bf16x8*)(buf + 8192 + xoff) = s;
      *(uint4*)(buf + woff0) = wr0;
      *(uint4*)(buf + woff1) = wr1;
    }

    // issue next-step loads; they stay in flight across the barrier
    if (i + 1 < NSTEP) {
      const int kn = (i + 1) * BK;
      xr0 = *(const float4*)(xg + kn);
      xr1 = *(const float4*)(xg + kn + 4);
      wr0 = *(const uint4*)(wg + kn);
      wr1 = *(const uint4*)(wg + kn + 8);
    }

    asm volatile("s_waitcnt lgkmcnt(0)" ::: "memory");  // ds_writes visible
    __builtin_amdgcn_s_barrier();                       // raw: does NOT drain vmcnt

    // fragments + MFMA from buf
#pragma unroll
    for (int kk = 0; kk < 2; ++kk) {
      const int col = kk * 32 + lk;
      bf16x8 af[2], bfv[4];
#pragma unroll
      for (int mi = 0; mi < 2; ++mi)
        af[mi] = *(const bf16x8*)(buf + abase + swz(ar0 + mi * 16, col));
#pragma unroll
      for (int ni = 0; ni < 4; ++ni)
        bfv[ni] = *(const bf16x8*)(buf + 16384 + swz(br0 + ni * 16, col));
#pragma unroll
      for (int mi = 0; mi < 2; ++mi)
#pragma unroll
        for (int ni = 0; ni < 4; ++ni)
          acc[mi][ni] = __builtin_amdgcn_mfma_f32_16x16x32_bf16(af[mi], bfv[ni],
                                                                acc[mi][ni], 0, 0, 0);
    }
    // no trailing barrier: next step writes the OTHER buffer; reuse of this
    // buffer (step i+2) is fenced by step i+1's lgkmcnt(0)+barrier.
  }

  // epilogue: write partial [kc][4096][256] f16 (m chunk ~0.07, v chunk <130:
  // f16 RNE error on final s is ~0.03 absolute, negligible vs 0.66 margin)
  _Float16* pp = partial + (size_t)kc * ((size_t)NB * 2 * D_OUT);
  const int crow = (lane >> 4) << 2;
  const int ccol = lane & 15;
#pragma unroll
  for (int mi = 0; mi < 2; ++mi) {
    const int grow = m0 + wm * 32 + mi * 16 + crow;
#pragma unroll
    for (int ni = 0; ni < 4; ++ni) {
      const int gcol = wn * 64 + ni * 16 + ccol;
      const f32x4 a = acc[mi][ni];
#pragma unroll
      for (int j = 0; j < 4; ++j)
        pp[(size_t)(grow + j) * (2 * D_OUT) + gcol] = (_Float16)a[j];
    }
  }
}

// ---------------------------------------------------------------------------
// reduce: sum K-chunk partials, out = m +/- eps*sqrt(v); block 0 sums KL
// ---------------------------------------------------------------------------
__global__ void reduce_kernel(const _Float16* __restrict__ partial,
                              const float* __restrict__ eps,
                              const float* __restrict__ kl_part,
                              float* __restrict__ out) {
  const int tid = blockIdx.x * blockDim.x + threadIdx.x;
  if (tid < NB * D_OUT / 4) {
    const int b = tid >> 5;
    const int j = (tid & 31) << 2;
    float m[4] = {0.f, 0.f, 0.f, 0.f}, v[4] = {0.f, 0.f, 0.f, 0.f};
#pragma unroll
    for (int q = 0; q < NKC; ++q) {
      const _Float16* p = partial + ((size_t)q * NB + b) * (2 * D_OUT);
      const half4 mm = *(const half4*)(p + j);
      const half4 vv = *(const half4*)(p + D_OUT + j);
#pragma unroll
      for (int k = 0; k < 4; ++k) {
        m[k] += (float)mm[k];
        v[k] += (float)vv[k];
      }
    }
    const float4 e4 = *(const float4*)(eps + (size_t)b * D_OUT + j);
    const float ev[4] = {e4.x, e4.y, e4.z, e4.w};
    float4 o0, o1;
    float* o0p = (float*)&o0;
    float* o1p = (float*)&o1;
#pragma unroll
    for (int jj = 0; jj < 4; ++jj) {
      const float s = ev[jj] * sqrtf(fmaxf(v[jj], 0.f));
      o0p[jj] = m[jj] + s;
      o1p[jj] = m[jj] - s;
    }
    *(float4*)(out + (size_t)b * D_OUT + j) = o0;
    *(float4*)(out + (size_t)NB * D_OUT + (size_t)b * D_OUT + j) = o1;
  }
  // block 0: deterministic KL sum over prep's 2048 partials
  if (blockIdx.x == 0) {
    float kl = 0.f;
    for (int i = threadIdx.x; i < PREP_BLOCKS; i += 256) kl += kl_part[i];
#pragma unroll
    for (int off = 32; off > 0; off >>= 1) kl += __shfl_down(kl, off);
    __shared__ float red[4];
    const int lane = threadIdx.x & 63;
    const int wid = threadIdx.x >> 6;
    if (lane == 0) red[wid] = kl;
    __syncthreads();
    if (threadIdx.x == 0)
      out[2 * NB * D_OUT] = (red[0] + red[1] + red[2] + red[3]) * (1.0f / 4096.0f);
  }
}

extern "C" void kernel_launch(void* const* d_in, const int* in_sizes, int n_in,
                              void* d_out, int out_size, void* d_ws, size_t ws_size,
                              hipStream_t stream) {
  const float* x   = (const float*)d_in[0];
  const float* mu  = (const float*)d_in[1];
  const float* sg  = (const float*)d_in[2];
  const float* sp  = (const float*)d_in[3];
  const float* pg  = (const float*)d_in[4];
  const float* eps = (const float*)d_in[5];
  float* out = (float*)d_out;

  // ws layout: [0,16MiB) bf16 weights [256][32768]; [16MiB,32MiB) partials
  // [8][4096][256] f16; [32MiB,+8KiB) kl partials [2048] f32
  __bf16* wcomb = (__bf16*)d_ws;
  _Float16* partial = (_Float16*)((char*)d_ws + (size_t)16 * 1024 * 1024);
  float* kl_part = (float*)((char*)d_ws + (size_t)32 * 1024 * 1024);

  prep_kernel<<<PREP_BLOCKS, 256, 0, stream>>>(mu, sg, sp, pg, wcomb, kl_part);
  gemm_kernel<<<(NB / BM) * NKC, 1024, 0, stream>>>(x, wcomb, partial);
  reduce_kernel<<<(NB * D_OUT / 4) / 256, 256, 0, stream>>>(partial, eps, kl_part, out);
}